// Round 1
// baseline (989.980 us; speedup 1.0000x reference)
//
#include <hip/hip_runtime.h>
#include <hip/hip_bf16.h>
#include <cstdio>
#include <cstdint>

#define B_    2
#define S_    2048
#define H_    32
#define KVH_  8
#define D_    128
#define HID_  4096
#define WIN_  512
#define NROW_ (B_*S_)          // 4096 rows for projection GEMMs
#define SCALE_ 0.08838834764831845f   // 128^-0.5

typedef __attribute__((ext_vector_type(8))) __bf16 bf16x8;
typedef __attribute__((ext_vector_type(4))) float  f32x4;

#define GAS __attribute__((address_space(1)))
#define LAS __attribute__((address_space(3)))

// ---------------------------------------------------------------- cvt f32->bf16
__global__ __launch_bounds__(256) void cvt_bf16(const float* __restrict__ in,
                                                __hip_bfloat16* __restrict__ out, int n) {
    int i = (blockIdx.x * 256 + threadIdx.x) * 4;
    if (i >= n) return;
    float4 v = *(const float4*)(in + i);
    __hip_bfloat162 a, b;
    a.x = __float2bfloat16(v.x); a.y = __float2bfloat16(v.y);
    b.x = __float2bfloat16(v.z); b.y = __float2bfloat16(v.w);
    *(__hip_bfloat162*)(out + i)     = a;
    *(__hip_bfloat162*)(out + i + 2) = b;
}

// ------------------------------------------------- transpose + cvt: (R,C) f32 -> (C,R) bf16
__global__ __launch_bounds__(256) void transpose_cvt(const float* __restrict__ in,
                                                     __hip_bfloat16* __restrict__ out,
                                                     int R, int C) {
    __shared__ float t[32][33];
    int tx = threadIdx.x, ty = threadIdx.y;             // (32,8)
    int r0 = blockIdx.y * 32, c0 = blockIdx.x * 32;
    #pragma unroll
    for (int i = 0; i < 4; ++i)
        t[ty + 8*i][tx] = in[(size_t)(r0 + ty + 8*i) * C + c0 + tx];
    __syncthreads();
    #pragma unroll
    for (int i = 0; i < 4; ++i)
        out[(size_t)(c0 + ty + 8*i) * R + r0 + tx] = __float2bfloat16(t[tx][ty + 8*i]);
}

// ------------------------------------------------- V: (B*S, KVH*D) f32 -> (B,KVH,D,S) bf16
__global__ __launch_bounds__(256) void v_transpose(const float* __restrict__ vf,
                                                   __hip_bfloat16* __restrict__ vt) {
    __shared__ float t[32][33];
    int tx = threadIdx.x, ty = threadIdx.y;             // (32,8)
    int plane = blockIdx.z, b = plane >> 3, g = plane & 7;
    int s0 = blockIdx.x * 32, d0 = blockIdx.y * 32;
    #pragma unroll
    for (int i = 0; i < 4; ++i) {
        int s = s0 + ty + 8*i;
        t[ty + 8*i][tx] = vf[((size_t)b*S_ + s) * (KVH_*D_) + g*D_ + d0 + tx];
    }
    __syncthreads();
    #pragma unroll
    for (int i = 0; i < 4; ++i) {
        int d = d0 + ty + 8*i;
        vt[(((size_t)b*KVH_ + g) * D_ + d) * S_ + s0 + tx] = __float2bfloat16(t[tx][ty + 8*i]);
    }
}

// ------------------------------------------------- GEMM: A(MxK) * Bt(NxK)^T -> C(MxN) f32
// m97 structure: 128x128 tile, BK=32, 4 waves (2x2), global_load_lds width-16 staging.
__global__ __launch_bounds__(256) void gemm_bt(const __hip_bfloat16* __restrict__ A,
                                               const __hip_bfloat16* __restrict__ Bt,
                                               float* __restrict__ C,
                                               int M, int N, int K) {
    __shared__ __align__(16) __hip_bfloat16 Asl[128*32];
    __shared__ __align__(16) __hip_bfloat16 Bsl[128*32];
    const int lane = threadIdx.x & 63, w = threadIdx.x >> 6;
    const int lc = lane & 15, lg = lane >> 4;
    const int row0 = blockIdx.y * 128, col0 = blockIdx.x * 128;
    const int wm = w >> 1, wn = w & 1;
    const int sr = lane >> 2, sc = (lane & 3) * 8;      // staging row/col within 16-row chunk

    f32x4 acc[4][4] = {};

    for (int kt = 0; kt < K; kt += 32) {
        #pragma unroll
        for (int i = 0; i < 2; ++i) {
            int c = w * 2 + i;                          // chunk 0..7 (16 rows x 32 cols = 1KB)
            const __hip_bfloat16* gA = A  + (size_t)(row0 + c*16 + sr) * K + kt + sc;
            __builtin_amdgcn_global_load_lds((const GAS void*)gA, (LAS void*)&Asl[c*512], 16, 0, 0);
            const __hip_bfloat16* gB = Bt + (size_t)(col0 + c*16 + sr) * K + kt + sc;
            __builtin_amdgcn_global_load_lds((const GAS void*)gB, (LAS void*)&Bsl[c*512], 16, 0, 0);
        }
        __syncthreads();
        bf16x8 af[4], bf[4];
        #pragma unroll
        for (int m = 0; m < 4; ++m)
            af[m] = *(const bf16x8*)&Asl[(wm*64 + m*16 + lc)*32 + lg*8];
        #pragma unroll
        for (int n = 0; n < 4; ++n)
            bf[n] = *(const bf16x8*)&Bsl[(wn*64 + n*16 + lc)*32 + lg*8];
        #pragma unroll
        for (int m = 0; m < 4; ++m)
            #pragma unroll
            for (int n = 0; n < 4; ++n)
                acc[m][n] = __builtin_amdgcn_mfma_f32_16x16x32_bf16(af[m], bf[n], acc[m][n], 0, 0, 0);
        __syncthreads();
    }
    #pragma unroll
    for (int m = 0; m < 4; ++m)
        #pragma unroll
        for (int n = 0; n < 4; ++n) {
            int col = col0 + wn*64 + n*16 + lc;
            #pragma unroll
            for (int r = 0; r < 4; ++r) {
                int row = row0 + wm*64 + m*16 + lg*4 + r;
                C[(size_t)row * N + col] = acc[m][n][r];
            }
        }
}

// ------------------------------------------------- per-head LN + interleaved RoPE
// in:  x (B*S, NH*D) f32 from GEMM.  out: (B, NH, S, D) bf16.
template <int NH>
__global__ __launch_bounds__(256) void ln_rope(const float* __restrict__ x,
                                               const float* __restrict__ wln,
                                               const float* __restrict__ cosT,
                                               const float* __restrict__ sinT,
                                               const int* __restrict__ pids,
                                               __hip_bfloat16* __restrict__ out) {
    const int lane = threadIdx.x & 63, wv = threadIdx.x >> 6;
    const int r = blockIdx.x * 4 + wv;                 // row over B*S*NH
    const int h = r % NH;
    const int bs = r / NH;
    const int b = bs / S_, s = bs % S_;
    const float2 xv = *(const float2*)(x + (size_t)r * D_ + lane*2);
    float sum = xv.x + xv.y;
    #pragma unroll
    for (int o = 32; o; o >>= 1) sum += __shfl_xor(sum, o);
    const float mu = sum * (1.f / D_);
    const float dx = xv.x - mu, dy = xv.y - mu;
    float vs = dx*dx + dy*dy;
    #pragma unroll
    for (int o = 32; o; o >>= 1) vs += __shfl_xor(vs, o);
    const float rs = rsqrtf(vs * (1.f / D_) + 1e-5f);
    const float2 w2 = *(const float2*)(wln + lane*2);
    const float y0 = w2.x * dx * rs, y1 = w2.y * dy * rs;
    const int p = pids[bs];
    const float2 c  = *(const float2*)(cosT + (size_t)p * D_ + lane*2);
    const float2 sn = *(const float2*)(sinT + (size_t)p * D_ + lane*2);
    __hip_bfloat162 ov;
    ov.x = __float2bfloat16(y0 * c.x - y1 * sn.x);     // even: x0*c - x1*s
    ov.y = __float2bfloat16(y1 * c.y + y0 * sn.y);     // odd:  x1*c + x0*s
    *(__hip_bfloat162*)(out + (((size_t)b * NH + h) * S_ + s) * D_ + lane*2) = ov;
}

// ------------------------------------------------- sliding-window GQA flash attention
// qr (B,H,S,D), kr (B,KVH,S,D), vt (B,KVH,D,S) bf16 -> ao (B,S,H*D) bf16.
// 1 wave = 16 q rows; 32-key tiles; online softmax; P via per-wave LDS round-trip.
__global__ __launch_bounds__(256) void attn_fwd(const __hip_bfloat16* __restrict__ qr,
                                                const __hip_bfloat16* __restrict__ kr,
                                                const __hip_bfloat16* __restrict__ vt,
                                                __hip_bfloat16* __restrict__ ao) {
    __shared__ __align__(16) __hip_bfloat16 plds[4][1024];   // per-wave, double-buffered 16x32
    const int lane = threadIdx.x & 63, w = threadIdx.x >> 6;
    const int lc = lane & 15, lg = lane >> 4;
    const int blk = blockIdx.x;
    const int qt = blk & (S_/64 - 1);
    const int bh = blk >> 5;
    const int h = bh & (H_-1), b = bh >> 5;
    const int g = h >> 2;                                    // GQA: kv head = h/4
    const int q0 = qt*64 + w*16;

    const __hip_bfloat16* qbase = qr + (((size_t)b*H_ + h)*S_ + q0) * D_;
    const __hip_bfloat16* kbase = kr + ((size_t)b*KVH_ + g) * (size_t)S_ * D_;
    const __hip_bfloat16* vbase = vt + ((size_t)b*KVH_ + g) * (size_t)D_ * S_;

    bf16x8 qf[4];
    #pragma unroll
    for (int kk = 0; kk < 4; ++kk)
        qf[kk] = *(const bf16x8*)(qbase + lc*D_ + kk*32 + lg*8);

    f32x4 o[8] = {};
    float mrow[4], lrow[4];
    #pragma unroll
    for (int r = 0; r < 4; ++r) { mrow[r] = -1e30f; lrow[r] = 0.f; }

    int kst = q0 - (WIN_ - 1); if (kst < 0) kst = 0; kst &= ~31;
    const int kend = q0 + 15;

    for (int k0 = kst; k0 <= kend; k0 += 32) {
        f32x4 s0 = {0.f,0.f,0.f,0.f}, s1 = {0.f,0.f,0.f,0.f};
        #pragma unroll
        for (int kk = 0; kk < 4; ++kk) {
            bf16x8 ka = *(const bf16x8*)(kbase + (size_t)(k0 + lc)      * D_ + kk*32 + lg*8);
            bf16x8 kb = *(const bf16x8*)(kbase + (size_t)(k0 + 16 + lc) * D_ + kk*32 + lg*8);
            s0 = __builtin_amdgcn_mfma_f32_16x16x32_bf16(qf[kk], ka, s0, 0, 0, 0);
            s1 = __builtin_amdgcn_mfma_f32_16x16x32_bf16(qf[kk], kb, s1, 0, 0, 0);
        }
        __hip_bfloat16* pl = plds[w] + ((k0 >> 5) & 1) * 512;
        float alpha[4];
        #pragma unroll
        for (int r = 0; r < 4; ++r) {
            const int row = q0 + lg*4 + r;
            const int ca = k0 + lc, cb = ca + 16;
            float va = (row >= ca && row - ca < WIN_) ? s0[r]*SCALE_ : -INFINITY;
            float vb = (row >= cb && row - cb < WIN_) ? s1[r]*SCALE_ : -INFINITY;
            float mx = fmaxf(va, vb);
            #pragma unroll
            for (int t = 8; t; t >>= 1) mx = fmaxf(mx, __shfl_xor(mx, t, 16));
            const float mn = fmaxf(mrow[r], mx);
            alpha[r] = __expf(mrow[r] - mn);
            const float pa = __expf(va - mn);        // masked: exp(-inf - finite) = 0
            const float pb = __expf(vb - mn);
            float ls = pa + pb;
            #pragma unroll
            for (int t = 8; t; t >>= 1) ls += __shfl_xor(ls, t, 16);
            lrow[r] = lrow[r]*alpha[r] + ls;
            mrow[r] = mn;
            pl[(lg*4 + r)*32 + lc]      = __float2bfloat16(pa);
            pl[(lg*4 + r)*32 + lc + 16] = __float2bfloat16(pb);
        }
        asm volatile("s_waitcnt lgkmcnt(0)" ::: "memory");
        __builtin_amdgcn_sched_barrier(0);
        const bf16x8 pf = *(const bf16x8*)(pl + lc*32 + lg*8);
        asm volatile("" ::: "memory");               // keep next-iter writes after this read
        #pragma unroll
        for (int n = 0; n < 8; ++n) {
            #pragma unroll
            for (int r = 0; r < 4; ++r) o[n][r] *= alpha[r];
            const bf16x8 vf8 = *(const bf16x8*)(vbase + (size_t)(n*16 + lc)*S_ + k0 + lg*8);
            o[n] = __builtin_amdgcn_mfma_f32_16x16x32_bf16(pf, vf8, o[n], 0, 0, 0);
        }
    }
    #pragma unroll
    for (int n = 0; n < 8; ++n)
        #pragma unroll
        for (int r = 0; r < 4; ++r) {
            const int row = q0 + lg*4 + r;
            ao[((size_t)b*S_ + row)*(H_*D_) + h*D_ + n*16 + lc] =
                __float2bfloat16(o[n][r] / lrow[r]);
        }
}

// ----------------------------------------------------------------- host
extern "C" void kernel_launch(void* const* d_in, const int* in_sizes, int n_in,
                              void* d_out, int out_size, void* d_ws, size_t ws_size,
                              hipStream_t stream) {
    const float* hidden = (const float*)d_in[0];
    const int*   pids   = (const int*)  d_in[1];
    const float* cosT   = (const float*)d_in[2];
    const float* sinT   = (const float*)d_in[3];
    const float* wq     = (const float*)d_in[4];
    const float* wk     = (const float*)d_in[5];
    const float* wv     = (const float*)d_in[6];
    const float* wo     = (const float*)d_in[7];
    const float* qnw    = (const float*)d_in[8];
    const float* knw    = (const float*)d_in[9];
    float* out = (float*)d_out;

    char* base = (char*)d_ws;
    size_t off = 0;
    auto take = [&](size_t bytes) -> void* {
        void* q = base + off;
        off = (off + bytes + 255) & ~(size_t)255;
        return q;
    };
    float* qf            = (float*)take((size_t)NROW_*HID_*4);          // also reused as ao
    __hip_bfloat16* hb   = (__hip_bfloat16*)take((size_t)NROW_*HID_*2);
    __hip_bfloat16* wqT  = (__hip_bfloat16*)take((size_t)HID_*HID_*2);
    __hip_bfloat16* wkT  = (__hip_bfloat16*)take((size_t)HID_*KVH_*D_*2);
    __hip_bfloat16* wvT  = (__hip_bfloat16*)take((size_t)HID_*KVH_*D_*2);
    __hip_bfloat16* woT  = (__hip_bfloat16*)take((size_t)HID_*HID_*2);
    float* kf            = (float*)take((size_t)NROW_*KVH_*D_*4);
    float* vf            = (float*)take((size_t)NROW_*KVH_*D_*4);
    __hip_bfloat16* qr   = (__hip_bfloat16*)take((size_t)B_*H_*S_*D_*2);
    __hip_bfloat16* kr   = (__hip_bfloat16*)take((size_t)B_*KVH_*S_*D_*2);
    __hip_bfloat16* vt   = (__hip_bfloat16*)take((size_t)B_*KVH_*S_*D_*2);
    __hip_bfloat16* ao   = (__hip_bfloat16*)qf;    // alias: qf dead after ln_rope

    if (off > ws_size) {
        fprintf(stderr, "WORKSPACE TOO SMALL: need %zu have %zu\n", off, ws_size);
        return;
    }

    // 1. converts / transposes
    cvt_bf16<<<(NROW_*HID_)/1024, 256, 0, stream>>>(hidden, hb, NROW_*HID_);
    transpose_cvt<<<dim3((H_*D_)/32,   HID_/32), dim3(32,8), 0, stream>>>(wq, wqT, HID_, H_*D_);
    transpose_cvt<<<dim3((KVH_*D_)/32, HID_/32), dim3(32,8), 0, stream>>>(wk, wkT, HID_, KVH_*D_);
    transpose_cvt<<<dim3((KVH_*D_)/32, HID_/32), dim3(32,8), 0, stream>>>(wv, wvT, HID_, KVH_*D_);
    transpose_cvt<<<dim3(HID_/32, (H_*D_)/32),   dim3(32,8), 0, stream>>>(wo, woT, H_*D_, HID_);

    // 2. QKV projections
    gemm_bt<<<dim3((H_*D_)/128,   NROW_/128), 256, 0, stream>>>(hb, wqT, qf, NROW_, H_*D_,   HID_);
    gemm_bt<<<dim3((KVH_*D_)/128, NROW_/128), 256, 0, stream>>>(hb, wkT, kf, NROW_, KVH_*D_, HID_);
    gemm_bt<<<dim3((KVH_*D_)/128, NROW_/128), 256, 0, stream>>>(hb, wvT, vf, NROW_, KVH_*D_, HID_);

    // 3. LN + RoPE (q, k), V transpose
    ln_rope<H_><<<(B_*S_*H_)/4,     256, 0, stream>>>(qf, qnw, cosT, sinT, pids, qr);
    ln_rope<KVH_><<<(B_*S_*KVH_)/4, 256, 0, stream>>>(kf, knw, cosT, sinT, pids, kr);
    v_transpose<<<dim3(S_/32, D_/32, B_*KVH_), dim3(32,8), 0, stream>>>(vf, vt);

    // 4. attention
    attn_fwd<<<B_*H_*(S_/64), 256, 0, stream>>>(qr, kr, vt, ao);

    // 5. output projection -> d_out (f32)
    gemm_bt<<<dim3(HID_/128, NROW_/128), 256, 0, stream>>>(ao, woT, out, NROW_, HID_, H_*D_ /*K=4096*/);
}